// Round 6
// baseline (233.299 us; speedup 1.0000x reference)
//
#include <hip/hip_runtime.h>
#include <hip/hip_bf16.h>

#define D 64   // D_IN == D_OUT == 64
#define M44 ((1ULL << 44) - 1)

// ---------------------------------------------------------------------------
// k1: zero both packed shards + counter
__global__ __launch_bounds__(256) void k_init(unsigned long long* __restrict__ packed0,
                                              unsigned long long* __restrict__ packed1,
                                              int* __restrict__ counter, int n) {
    int i = blockIdx.x * 256 + threadIdx.x;
    if (i < n) { packed0[i] = 0ULL; packed1[i] = 0ULL; }
    if (i == 0) *counter = 0;
}

// k2: ONE 64-bit atomic per edge into shard (blockIdx&1). high 20 bits =
// count, low 44 = fixed-point(2^-32) sum of ew. Returned old -> per-shard rank.
// 2-way sharding halves cache-line contention (diagnostic: if k_count is
// line-contention-bound this should drop ~2x; if RMW-throughput-bound, flat).
__global__ __launch_bounds__(256) void k_count(const int* __restrict__ rowi,
                                               const float* __restrict__ ew,
                                               unsigned long long* __restrict__ packed0,
                                               unsigned long long* __restrict__ packed1,
                                               int* __restrict__ rank, int nE) {
    int e = blockIdx.x * 256 + threadIdx.x;
    if (e < nE) {
        unsigned long long* P = (blockIdx.x & 1) ? packed1 : packed0;
        unsigned long long fx = (unsigned long long)((double)ew[e] * 4294967296.0);
        unsigned long long old = atomicAdd(&P[rowi[e]], (1ULL << 44) | fx);
        rank[e] = (int)(old >> 44);
    }
}

// k3: merge shards: deg=1+sum(fx), dis=rsqrt(deg); wave-scan of total counts
// -> one atomic per wave; start0 = global segment start, start1 = start0+c0.
__global__ __launch_bounds__(256) void k_scan(const unsigned long long* __restrict__ packed0,
                                              const unsigned long long* __restrict__ packed1,
                                              float* __restrict__ dis,
                                              int* __restrict__ cnt,
                                              int* __restrict__ start0,
                                              int* __restrict__ start1,
                                              int* __restrict__ counter, int n) {
    int i = blockIdx.x * 256 + threadIdx.x;
    int lane = threadIdx.x & 63;
    unsigned long long p0 = (i < n) ? packed0[i] : 0ULL;
    unsigned long long p1 = (i < n) ? packed1[i] : 0ULL;
    int c0 = (int)(p0 >> 44);
    int c  = c0 + (int)(p1 >> 44);
    unsigned long long fx = (p0 & M44) + (p1 & M44);
    if (i < n) {
        float dg = (float)(1.0 + (double)fx * (1.0 / 4294967296.0));
        dis[i] = rsqrtf(dg);
        cnt[i] = c;
    }
    int incl = c;
#pragma unroll
    for (int o = 1; o < 64; o <<= 1) {
        int t = __shfl_up(incl, o, 64);
        if (lane >= o) incl += t;
    }
    int total = __shfl(incl, 63, 64);
    int base = 0;
    if (lane == 0) base = atomicAdd(counter, total);
    base = __shfl(base, 0, 64);
    if (i < n) {
        int s = base + incl - c;
        start0[i] = s;
        start1[i] = s + c0;
    }
}

// k4a (main): placement storing RAW ew — no dis[col] random load.
__global__ __launch_bounds__(256) void k_place_xs(const int* __restrict__ rowi,
                                                  const int* __restrict__ coli,
                                                  const float* __restrict__ ew,
                                                  const int* __restrict__ start0,
                                                  const int* __restrict__ start1,
                                                  const int* __restrict__ rank,
                                                  int2* __restrict__ scw, int nE) {
    int e = blockIdx.x * 256 + threadIdx.x;
    if (e < nE) {
        int r = rowi[e];
        int s = ((e >> 8) & 1) ? start1[r] : start0[r];   // same shard map as k_count
        scw[s + rank[e]] = make_int2(coli[e], __float_as_int(ew[e]));
    }
}

// k4b (fallback): round-5 style, folds dis[col] into the weight.
__global__ __launch_bounds__(256) void k_place_dis(const int* __restrict__ rowi,
                                                   const int* __restrict__ coli,
                                                   const float* __restrict__ ew,
                                                   const float* __restrict__ dis,
                                                   const int* __restrict__ start0,
                                                   const int* __restrict__ start1,
                                                   const int* __restrict__ rank,
                                                   int2* __restrict__ scw, int nE) {
    int e = blockIdx.x * 256 + threadIdx.x;
    if (e < nE) {
        int r = rowi[e];
        int c = coli[e];
        int s = ((e >> 8) & 1) ? start1[r] : start0[r];
        scw[s + rank[e]] = make_int2(c, __float_as_int(ew[e] * dis[c]));
    }
}

// k5 (main): xs[i][:] = x[i][:] * dis[i]  — pure streaming 51MB.
__global__ __launch_bounds__(256) void k_scale(const float* __restrict__ x,
                                               const float* __restrict__ dis,
                                               float* __restrict__ xs, int n) {
    int g = blockIdx.x * 256 + threadIdx.x;
    int i = g >> 4;
    if (i >= n) return;
    float di = dis[i];
    float4 xv = ((const float4*)x)[g];
    float4 o; o.x = xv.x * di; o.y = xv.y * di; o.z = xv.z * di; o.w = xv.w * di;
    ((float4*)xs)[g] = o;
}

// k6a (main): gather over pre-scaled xs: out_i = dis_i * (sum ew*xs[col] + xs_i)
__global__ __launch_bounds__(256) void k_gather_xs(const float* __restrict__ xs,
                                                   const float* __restrict__ dis,
                                                   const int* __restrict__ start0,
                                                   const int* __restrict__ cnt,
                                                   const int2* __restrict__ scw,
                                                   float* __restrict__ agg, int n) {
    int g = blockIdx.x * 256 + threadIdx.x;
    int i = g >> 4;
    if (i >= n) return;
    int j = g & 15;

    const float4* x4 = (const float4*)xs;
    float4 acc = make_float4(0.f, 0.f, 0.f, 0.f);
    int s = start0[i];
    int e_end = s + cnt[i];
    for (int e = s; e < e_end; e += 16) {
        int idx = e + j;
        int2 v = make_int2(0, 0);
        if (idx < e_end) v = scw[idx];
        int m = e_end - e; if (m > 16) m = 16;
#pragma unroll
        for (int t = 0; t < 16; ++t) {
            if (t < m) {
                int col = __shfl(v.x, t, 16);
                float w = __int_as_float(__shfl(v.y, t, 16));
                float4 xv = x4[col * 16 + j];
                acc.x += w * xv.x; acc.y += w * xv.y;
                acc.z += w * xv.z; acc.w += w * xv.w;
            }
        }
    }
    float di = dis[i];
    float4 xi = x4[i * 16 + j];
    float4 o;
    o.x = di * (acc.x + xi.x); o.y = di * (acc.y + xi.y);
    o.z = di * (acc.z + xi.z); o.w = di * (acc.w + xi.w);
    ((float4*)agg)[i * 16 + j] = o;
}

// k6b (fallback): gather over raw x (weights already include dis[col]):
// out_i = dis_i * (dis_i * x_i + acc)
__global__ __launch_bounds__(256) void k_gather_x(const float* __restrict__ x,
                                                  const float* __restrict__ dis,
                                                  const int* __restrict__ start0,
                                                  const int* __restrict__ cnt,
                                                  const int2* __restrict__ scw,
                                                  float* __restrict__ agg, int n) {
    int g = blockIdx.x * 256 + threadIdx.x;
    int i = g >> 4;
    if (i >= n) return;
    int j = g & 15;

    const float4* x4 = (const float4*)x;
    float4 acc = make_float4(0.f, 0.f, 0.f, 0.f);
    int s = start0[i];
    int e_end = s + cnt[i];
    for (int e = s; e < e_end; e += 16) {
        int idx = e + j;
        int2 v = make_int2(0, 0);
        if (idx < e_end) v = scw[idx];
        int m = e_end - e; if (m > 16) m = 16;
#pragma unroll
        for (int t = 0; t < 16; ++t) {
            if (t < m) {
                int col = __shfl(v.x, t, 16);
                float w = __int_as_float(__shfl(v.y, t, 16));
                float4 xv = x4[col * 16 + j];
                acc.x += w * xv.x; acc.y += w * xv.y;
                acc.z += w * xv.z; acc.w += w * xv.w;
            }
        }
    }
    float di = dis[i];
    float4 xi = x4[i * 16 + j];
    float4 o;
    o.x = di * (di * xi.x + acc.x); o.y = di * (di * xi.y + acc.y);
    o.z = di * (di * xi.z + acc.z); o.w = di * (di * xi.w + acc.w);
    ((float4*)agg)[i * 16 + j] = o;
}

// k7: out = A @ W^T + bias. Round-5 kernel (proven: left top-5). Swizzled LDS,
// no padding, launch_bounds(256,4) caps VGPR. In-place safe (stages via LDS).
__global__ __launch_bounds__(256, 4) void gcn_gemm(const float* __restrict__ agg,
                                                   const float* __restrict__ W,
                                                   const float* __restrict__ bias,
                                                   float* __restrict__ out, int n) {
    __shared__ float Ast[D * D];
    __shared__ float Bs[D * D];
    float4* Ast4 = (float4*)Ast;
    int tid = threadIdx.x;
    int r0 = blockIdx.x * 64;

    const float4* W4 = (const float4*)W;
    const float4* A4 = (const float4*)agg;
#pragma unroll
    for (int v = 0; v < 4; ++v) {
        int idx = tid + v * 256;
        int a  = idx >> 4;
        int kc = idx & 15;
        int ra = r0 + a;
        float4 av = make_float4(0.f, 0.f, 0.f, 0.f);
        if (ra < n) av = A4[ra * 16 + kc];
        Ast4[a * 16 + ((kc + (a >> 2)) & 15)] = av;
        float4 wv = W4[idx];
        int gq = a >> 2, oo = a & 3;
        { int k = 4 * kc + 0; Bs[k * 64 + 4 * ((gq + k) & 15) + oo] = wv.x; }
        { int k = 4 * kc + 1; Bs[k * 64 + 4 * ((gq + k) & 15) + oo] = wv.y; }
        { int k = 4 * kc + 2; Bs[k * 64 + 4 * ((gq + k) & 15) + oo] = wv.z; }
        { int k = 4 * kc + 3; Bs[k * 64 + 4 * ((gq + k) & 15) + oo] = wv.w; }
    }
    __syncthreads();

    int ty = tid >> 4;
    int tx = tid & 15;
    float acc[4][4];
#pragma unroll
    for (int m = 0; m < 4; ++m)
#pragma unroll
        for (int q = 0; q < 4; ++q) acc[m][q] = 0.f;

#pragma unroll 4
    for (int kc = 0; kc < 16; ++kc) {
        float4 a4[4], b4[4];
#pragma unroll
        for (int m = 0; m < 4; ++m)
            a4[m] = Ast4[(4 * ty + m) * 16 + ((kc + ty) & 15)];
#pragma unroll
        for (int i = 0; i < 4; ++i) {
            int k = 4 * kc + i;
            b4[i] = *(const float4*)&Bs[k * 64 + 4 * ((tx + k) & 15)];
        }
#pragma unroll
        for (int m = 0; m < 4; ++m) {
            acc[m][0] += a4[m].x * b4[0].x + a4[m].y * b4[1].x + a4[m].z * b4[2].x + a4[m].w * b4[3].x;
            acc[m][1] += a4[m].x * b4[0].y + a4[m].y * b4[1].y + a4[m].z * b4[2].y + a4[m].w * b4[3].y;
            acc[m][2] += a4[m].x * b4[0].z + a4[m].y * b4[1].z + a4[m].z * b4[2].z + a4[m].w * b4[3].z;
            acc[m][3] += a4[m].x * b4[0].w + a4[m].y * b4[1].w + a4[m].z * b4[2].w + a4[m].w * b4[3].w;
        }
    }

    float4 bv = ((const float4*)bias)[tx];
    float4* out4 = (float4*)out;
#pragma unroll
    for (int m = 0; m < 4; ++m) {
        int r = r0 + 4 * ty + m;
        if (r < n) {
            float4 o;
            o.x = acc[m][0] + bv.x; o.y = acc[m][1] + bv.y;
            o.z = acc[m][2] + bv.z; o.w = acc[m][3] + bv.w;
            out4[r * 16 + tx] = o;
        }
    }
}

extern "C" void kernel_launch(void* const* d_in, const int* in_sizes, int n_in,
                              void* d_out, int out_size, void* d_ws, size_t ws_size,
                              hipStream_t stream) {
    const float* x    = (const float*)d_in[0];
    const int*   ei   = (const int*)d_in[1];
    const float* ew   = (const float*)d_in[2];
    const float* W    = (const float*)d_in[3];
    const float* bias = (const float*)d_in[4];
    float* out = (float*)d_out;

    int n  = in_sizes[0] / D;   // 100000
    int nE = in_sizes[2];       // 1000000
    const int* rowi = ei;
    const int* coli = ei + nE;

    size_t aggB   = (size_t)n * D * sizeof(float);        // 25.6 MB
    size_t needXs = aggB + (size_t)nE * 8 + 4 * (size_t)n * 4 + 256;

    int gn  = (n + 255) / 256;
    int gE  = (nE + 255) / 256;
    int gNd = (n * 16 + 255) / 256;

    if (ws_size >= needXs) {
        // MAIN: agg region at ws start; packed0/packed1/rank overlay inside it
        // (they die before gather writes agg). xs lives in d_out (overwritten
        // by gemm at the end). ~35.2 MB ws.
        char* w = (char*)d_ws;
        float* agg = (float*)w;
        unsigned long long* packed0 = (unsigned long long*)w;
        unsigned long long* packed1 = packed0 + n;
        int* rank = (int*)(packed1 + n);
        char* w2 = w + aggB;
        int2*  scw     = (int2*)w2;   w2 += (size_t)nE * 8;
        float* dis     = (float*)w2;  w2 += (size_t)n * 4;
        int*   cnt     = (int*)w2;    w2 += (size_t)n * 4;
        int*   start0  = (int*)w2;    w2 += (size_t)n * 4;
        int*   start1  = (int*)w2;    w2 += (size_t)n * 4;
        int*   counter = (int*)w2;
        float* xs = out;

        k_init    <<<gn, 256, 0, stream>>>(packed0, packed1, counter, n);
        k_count   <<<gE, 256, 0, stream>>>(rowi, ew, packed0, packed1, rank, nE);
        k_scan    <<<gn, 256, 0, stream>>>(packed0, packed1, dis, cnt, start0, start1, counter, n);
        k_place_xs<<<gE, 256, 0, stream>>>(rowi, coli, ew, start0, start1, rank, scw, nE);
        k_scale   <<<gNd, 256, 0, stream>>>(x, dis, xs, n);
        k_gather_xs<<<gNd, 256, 0, stream>>>(xs, dis, start0, cnt, scw, agg, n);
        gcn_gemm  <<<(n + 63) / 64, 256, 0, stream>>>(agg, W, bias, out, n);
    } else {
        // FALLBACK (~15.2 MB ws): round-5 semantics, agg in-place in d_out.
        char* w = (char*)d_ws;
        unsigned long long* packed0 = (unsigned long long*)w; w += (size_t)n * 8;
        unsigned long long* packed1 = (unsigned long long*)w; w += (size_t)n * 8;
        int2*  scw     = (int2*)w;   w += (size_t)nE * 8;
        int*   rank    = (int*)w;    w += (size_t)nE * 4;
        float* dis     = (float*)w;  w += (size_t)n * 4;
        int*   cnt     = (int*)w;    w += (size_t)n * 4;
        int*   start0  = (int*)w;    w += (size_t)n * 4;
        int*   start1  = (int*)w;    w += (size_t)n * 4;
        int*   counter = (int*)w;

        k_init     <<<gn, 256, 0, stream>>>(packed0, packed1, counter, n);
        k_count    <<<gE, 256, 0, stream>>>(rowi, ew, packed0, packed1, rank, nE);
        k_scan     <<<gn, 256, 0, stream>>>(packed0, packed1, dis, cnt, start0, start1, counter, n);
        k_place_dis<<<gE, 256, 0, stream>>>(rowi, coli, ew, dis, start0, start1, rank, scw, nE);
        k_gather_x <<<gNd, 256, 0, stream>>>(x, dis, start0, cnt, scw, out, n);
        gcn_gemm   <<<(n + 63) / 64, 256, 0, stream>>>(out, W, bias, out, n);
    }
}